// Round 18
// baseline (133.011 us; speedup 1.0000x reference)
//
#include <hip/hip_runtime.h>

#define S_DIM 512
#define B_DIM 16384
#define A_DIM 2
#define BA (B_DIM * A_DIM)   // 32768
#define HID 16
#define EMB 8
#define NPART 1000
#define TABN (NPART * HID)   // 16000
#define NGTOT (S_DIM / 4)    // 128 groups of 4 steps total
#define SCALE 2.8853900817779268f   // 2*log2(e): folded into proj/wa/wb
// Balanced 2-way time-split (R16, best measured): seg0 outputs [0,67);
// seg1 warms up [61,67) (24 steps, contraction ~1e-5) then outputs [67,128).

// Kernel 1: proj[p][j] = SCALE * (b1[j] + sum_k emb_table[p][k] * W1[2+k][j])
__global__ __launch_bounds__(256) void emb_proj_kernel(
    const float* __restrict__ emb_table, const float* __restrict__ W1,
    const float* __restrict__ b1, float* __restrict__ proj) {
  int idx = blockIdx.x * 256 + threadIdx.x;
  if (idx >= TABN) return;
  int p = idx >> 4;
  int j = idx & 15;
  float acc = b1[j];
#pragma unroll
  for (int k = 0; k < EMB; ++k)
    acc = fmaf(emb_table[p * EMB + k], W1[(2 + k) * HID + j], acc);
  proj[idx] = acc * SCALE;
}

// DPP quad-perm (pure VALU)
template <int CTRL>
__device__ __forceinline__ int dppi(int x) {
  return __builtin_amdgcn_update_dpp(0, x, CTRL, 0xF, 0xF, true);
}
template <int CTRL>
__device__ __forceinline__ float dppf(float x) {
  return __builtin_bit_cast(float, dppi<CTRL>(__builtin_bit_cast(int, x)));
}
#define BC(K) ((K) | ((K) << 2) | ((K) << 4) | ((K) << 6))  // bcast lane K of quad

// Scan: R16 structure EXACTLY (2-way balanced split, 4 waves/SIMD,
// compile-time loops) + batched-rcp tanh (R13 math): the 4 tanh
// reciprocals share ONE v_rcp via exclusion products. Trans 10 -> 7 per
// lane-step. R17 proved the regime is issue-saturated (VALUBusy pinned at
// 72.5% for 4 AND 8 waves/SIMD) -> issue-cycle cuts convert directly to
// wall; the longer dep chain that killed R13 at 2 waves is now hidden.
__global__ __launch_bounds__(256, 4) void scan_kernel(
    const int* __restrict__ act, const float* __restrict__ rew,
    const int* __restrict__ pid, const float* __restrict__ W1,
    const float* __restrict__ W2, const float* __restrict__ b2,
    const float* __restrict__ proj, float* __restrict__ out) {
  int blk = blockIdx.x;                    // 0..1023
  int seg = blk >> 9;                      // 0 or 1 (block-uniform)
  int tt = (blk & 511) * 256 + threadIdx.x;  // 0..131071
  int chain = tt >> 2;                     // 0..32767 (= b*A + a)
  int sub = tt & 3;
  int b = chain >> 1;
  int j0 = sub << 2;

  float4 wav = *(const float4*)(W1 + j0);        // W1[0][j], scaled
  float4 wbv = *(const float4*)(W1 + HID + j0);  // W1[1][j], scaled
  float4 w2v = *(const float4*)(W2 + j0);        // W2[j][0] (NOT scaled)
  wav.x *= SCALE; wav.y *= SCALE; wav.z *= SCALE; wav.w *= SCALE;
  wbv.x *= SCALE; wbv.y *= SCALE; wbv.z *= SCALE; wbv.w *= SCALE;
  float bb2 = b2[0];

  const float* rp = rew + chain;
  const int* ap = act + chain;
  const int* pp = pid + b;
  const float* tbl = proj + j0;
  float* op = out + chain;

#define LOAD_RAW(G_, RD, AD, PD)                  \
  {                                               \
    int gg_ = (G_) < NGTOT ? (G_) : NGTOT - 1;    \
    size_t st_ = (size_t)(gg_ * 4 + sub);         \
    RD = rp[st_ * BA];                            \
    AD = ap[st_ * BA];                            \
    PD = pp[st_ * B_DIM];                         \
  }

#define GATHER(PS, T0, T1, T2, T3)            \
  {                                           \
    int pq0_ = dppi<BC(0)>(PS);               \
    int pq1_ = dppi<BC(1)>(PS);               \
    int pq2_ = dppi<BC(2)>(PS);               \
    int pq3_ = dppi<BC(3)>(PS);               \
    T0 = *(const float4*)(tbl + pq0_ * HID);  \
    T1 = *(const float4*)(tbl + pq1_ * HID);  \
    T2 = *(const float4*)(tbl + pq2_ * HID);  \
    T3 = *(const float4*)(tbl + pq3_ * HID);  \
  }

// One step. P_ = prefolded scaled input (r*wb' + T'). x' clamped [0,24]
// (v_med3; keeps 4-denominator product < 1e29). d_j = exp2(x'_j)+1;
// h_j = 1 - 2/d_j; the four 1/d_j share ONE rcp via exclusion products.
#define STEP(P_, AF_, STO_)                                             \
  {                                                                     \
    float x0_k = fmaf(state, wav.x, P_.x);                              \
    float x1_k = fmaf(state, wav.y, P_.y);                              \
    float x2_k = fmaf(state, wav.z, P_.z);                              \
    float x3_k = fmaf(state, wav.w, P_.w);                              \
    x0_k = fminf(fmaxf(x0_k, 0.f), 24.f);                               \
    x1_k = fminf(fmaxf(x1_k, 0.f), 24.f);                               \
    x2_k = fminf(fmaxf(x2_k, 0.f), 24.f);                               \
    x3_k = fminf(fmaxf(x3_k, 0.f), 24.f);                               \
    float d0_k = __builtin_amdgcn_exp2f(x0_k) + 1.f;                    \
    float d1_k = __builtin_amdgcn_exp2f(x1_k) + 1.f;                    \
    float d2_k = __builtin_amdgcn_exp2f(x2_k) + 1.f;                    \
    float d3_k = __builtin_amdgcn_exp2f(x3_k) + 1.f;                    \
    float p01_k = d0_k * d1_k, p23_k = d2_k * d3_k;                     \
    float inv_k = __builtin_amdgcn_rcpf(p01_k * p23_k);                 \
    float i01_k = inv_k * p23_k, i23_k = inv_k * p01_k;                 \
    float h0_k = fmaf(-2.f, i01_k * d1_k, 1.f);                         \
    float h1_k = fmaf(-2.f, i01_k * d0_k, 1.f);                         \
    float h2_k = fmaf(-2.f, i23_k * d3_k, 1.f);                         \
    float h3_k = fmaf(-2.f, i23_k * d2_k, 1.f);                         \
    float s0_k = fmaf(h0_k, w2v.x, h1_k * w2v.y);                       \
    float s1_k = fmaf(h2_k, w2v.z, h3_k * w2v.w);                       \
    float ps_k = s0_k + s1_k;                                           \
    ps_k += dppf<0xB1>(ps_k); /* xor1 */                                \
    ps_k += dppf<0x4E>(ps_k); /* xor2 */                                \
    float z_k = fmaf(AF_, ps_k + bb2, state); /* AF_ in {0.,1.} */      \
    state = __builtin_amdgcn_rcpf(                                      \
        1.f + __builtin_amdgcn_exp2f(z_k * -1.4426950408889634f));      \
    STO_ = state;                                                       \
  }

#define PROLOGUE(G0_)                 \
  LOAD_RAW(G0_, rA, aA, pA);          \
  LOAD_RAW((G0_) + 1, rB, aB, pB);    \
  GATHER(pA, t0, t1, t2, t3);

// One group-of-4 loop with LITERAL bounds. DOST_ is a literal 0/1.
#define SCAN_LOOP(G0_, G1_, DOST_)                                     \
  _Pragma("unroll 2")                                                  \
  for (int g = G0_; g < G1_; ++g) {                                    \
    LOAD_RAW(g + 2, rC, aC, pC);       /* raw: 2-group lead */         \
    float4 u0, u1, u2, u3;                                             \
    GATHER(pB, u0, u1, u2, u3);        /* table: 1-group lead */       \
    float r0 = dppf<BC(0)>(rA), r1 = dppf<BC(1)>(rA);                  \
    float r2 = dppf<BC(2)>(rA), r3 = dppf<BC(3)>(rA);                  \
    float afq = (float)aA;                                             \
    float af0 = dppf<BC(0)>(afq), af1 = dppf<BC(1)>(afq);              \
    float af2 = dppf<BC(2)>(afq), af3 = dppf<BC(3)>(afq);              \
    float4 p0, p1, p2, p3;                                             \
    p0.x = fmaf(r0, wbv.x, t0.x); p0.y = fmaf(r0, wbv.y, t0.y);        \
    p0.z = fmaf(r0, wbv.z, t0.z); p0.w = fmaf(r0, wbv.w, t0.w);        \
    p1.x = fmaf(r1, wbv.x, t1.x); p1.y = fmaf(r1, wbv.y, t1.y);        \
    p1.z = fmaf(r1, wbv.z, t1.z); p1.w = fmaf(r1, wbv.w, t1.w);        \
    p2.x = fmaf(r2, wbv.x, t2.x); p2.y = fmaf(r2, wbv.y, t2.y);        \
    p2.z = fmaf(r2, wbv.z, t2.z); p2.w = fmaf(r2, wbv.w, t2.w);        \
    p3.x = fmaf(r3, wbv.x, t3.x); p3.y = fmaf(r3, wbv.y, t3.y);        \
    p3.z = fmaf(r3, wbv.z, t3.z); p3.w = fmaf(r3, wbv.w, t3.w);        \
    float s0, s1, s2, s3;                                              \
    STEP(p0, af0, s0);                                                 \
    STEP(p1, af1, s1);                                                 \
    STEP(p2, af2, s2);                                                 \
    STEP(p3, af3, s3);                                                 \
    if (DOST_) {                                                       \
      float sv = (sub & 1) ? s1 : s0;                                  \
      float sw = (sub & 1) ? s3 : s2;                                  \
      sv = (sub & 2) ? sw : sv;                                        \
      op[(size_t)(g * 4 + sub) * BA] = sv;                             \
    }                                                                  \
    rA = rB; aA = aB;                                                  \
    rB = rC; aB = aC; pB = pC;                                         \
    t0 = u0; t1 = u1; t2 = u2; t3 = u3;                                \
  }

  float rA, rB, rC;
  int aA, aB, aC, pA, pB, pC;
  float4 t0, t1, t2, t3;
  float state;

  if (seg == 0) {
    state = 0.f;
    PROLOGUE(0);
    SCAN_LOOP(0, 67, 1);    // 67 groups of work
  } else {
    state = 0.5f;  // contraction warm-up init
    PROLOGUE(61);
    SCAN_LOOP(61, 67, 0);   // 24 warm-up steps, no stores
    SCAN_LOOP(67, 128, 1);  // output steps 268..511 -> 67 groups total
  }
}

extern "C" void kernel_launch(void* const* d_in, const int* in_sizes, int n_in,
                              void* d_out, int out_size, void* d_ws, size_t ws_size,
                              hipStream_t stream) {
  const int* c_Action = (const int*)d_in[0];
  const float* c_Reward = (const float*)d_in[1];
  const int* c_ParticipantID = (const int*)d_in[2];
  const float* emb_table = (const float*)d_in[3];
  const float* W1 = (const float*)d_in[4];
  const float* b1 = (const float*)d_in[5];
  const float* W2 = (const float*)d_in[6];
  const float* b2 = (const float*)d_in[7];
  float* out = (float*)d_out;
  float* proj = (float*)d_ws;  // 16000 floats = 64 KB scratch

  emb_proj_kernel<<<(TABN + 255) / 256, 256, 0, stream>>>(emb_table, W1, b1, proj);

  // 32768 chains * 4 lanes * 2 balanced time-segments = 262144 threads;
  // 1024 blocks -> 4 waves/SIMD
  scan_kernel<<<1024, 256, 0, stream>>>(
      c_Action, c_Reward, c_ParticipantID, W1, W2, b2, proj, out);
}

// Round 19
// 113.222 us; speedup vs baseline: 1.1748x; 1.1748x over previous
//
#include <hip/hip_runtime.h>

#define S_DIM 512
#define B_DIM 16384
#define A_DIM 2
#define BA (B_DIM * A_DIM)   // 32768
#define HID 16
#define EMB 8
#define NPART 1000
#define TABN (NPART * HID)   // 16000
#define NGTOT (S_DIM / 4)    // 128 groups of 4 steps total
#define SCALE 2.8853900817779268f   // 2*log2(e): folded into proj/wa/wb
// Balanced 2-way time-split (R16, best measured): seg0 outputs [0,67);
// seg1 warms up [61,67) (24 steps, contraction ~1e-5) then outputs [67,128).

// Kernel 1: proj[p][j] = SCALE * (b1[j] + sum_k emb_table[p][k] * W1[2+k][j])
__global__ __launch_bounds__(256) void emb_proj_kernel(
    const float* __restrict__ emb_table, const float* __restrict__ W1,
    const float* __restrict__ b1, float* __restrict__ proj) {
  int idx = blockIdx.x * 256 + threadIdx.x;
  if (idx >= TABN) return;
  int p = idx >> 4;
  int j = idx & 15;
  float acc = b1[j];
#pragma unroll
  for (int k = 0; k < EMB; ++k)
    acc = fmaf(emb_table[p * EMB + k], W1[(2 + k) * HID + j], acc);
  proj[idx] = acc * SCALE;
}

// DPP quad-perm (pure VALU)
template <int CTRL>
__device__ __forceinline__ int dppi(int x) {
  return __builtin_amdgcn_update_dpp(0, x, CTRL, 0xF, 0xF, true);
}
template <int CTRL>
__device__ __forceinline__ float dppf(float x) {
  return __builtin_bit_cast(float, dppi<CTRL>(__builtin_bit_cast(int, x)));
}
#define BC(K) ((K) | ((K) << 2) | ((K) << 4) | ((K) << 6))  // bcast lane K of quad

// Scan: R16 structure EXACTLY (2-way balanced split, 4 waves/SIMD, literal
// loops) + dot-folded tanh: sum(h*w2) = sum(w2) - sum(2*w2/(e+1)), so the
// step is rcp -> fma-dot directly (w2n = -2*w2 precomputed; sum(w2)+bb2
// folded into one scalar). -4 issue slots and -1 dep stage per lane-step.
// Issue model (R18 calibrated): trans ops cost the SAME 2cy issue slot as
// VALU; R16 was 94% issue-bound at 80 slots/step -> this is ~70.
__global__ __launch_bounds__(256, 4) void scan_kernel(
    const int* __restrict__ act, const float* __restrict__ rew,
    const int* __restrict__ pid, const float* __restrict__ W1,
    const float* __restrict__ W2, const float* __restrict__ b2,
    const float* __restrict__ proj, float* __restrict__ out) {
  int blk = blockIdx.x;                    // 0..1023
  int seg = blk >> 9;                      // 0 or 1 (block-uniform)
  int tt = (blk & 511) * 256 + threadIdx.x;  // 0..131071
  int chain = tt >> 2;                     // 0..32767 (= b*A + a)
  int sub = tt & 3;
  int b = chain >> 1;
  int j0 = sub << 2;

  float4 wav = *(const float4*)(W1 + j0);        // W1[0][j], scaled
  float4 wbv = *(const float4*)(W1 + HID + j0);  // W1[1][j], scaled
  float4 w2v = *(const float4*)(W2 + j0);        // W2[j][0]
  wav.x *= SCALE; wav.y *= SCALE; wav.z *= SCALE; wav.w *= SCALE;
  wbv.x *= SCALE; wbv.y *= SCALE; wbv.z *= SCALE; wbv.w *= SCALE;
  // dot folding: w2n = -2*w2 ; W2pb = sum_16(w2) + b2  (reduce once here)
  float4 w2n;
  w2n.x = -2.f * w2v.x; w2n.y = -2.f * w2v.y;
  w2n.z = -2.f * w2v.z; w2n.w = -2.f * w2v.w;
  float w2s = (w2v.x + w2v.y) + (w2v.z + w2v.w);
  w2s += dppf<0xB1>(w2s);
  w2s += dppf<0x4E>(w2s);
  float W2pb = w2s + b2[0];

  const float* rp = rew + chain;
  const int* ap = act + chain;
  const int* pp = pid + b;
  const float* tbl = proj + j0;
  float* op = out + chain;

#define LOAD_RAW(G_, RD, AD, PD)                  \
  {                                               \
    int gg_ = (G_) < NGTOT ? (G_) : NGTOT - 1;    \
    size_t st_ = (size_t)(gg_ * 4 + sub);         \
    RD = rp[st_ * BA];                            \
    AD = ap[st_ * BA];                            \
    PD = pp[st_ * B_DIM];                         \
  }

#define GATHER(PS, T0, T1, T2, T3)            \
  {                                           \
    int pq0_ = dppi<BC(0)>(PS);               \
    int pq1_ = dppi<BC(1)>(PS);               \
    int pq2_ = dppi<BC(2)>(PS);               \
    int pq3_ = dppi<BC(3)>(PS);               \
    T0 = *(const float4*)(tbl + pq0_ * HID);  \
    T1 = *(const float4*)(tbl + pq1_ * HID);  \
    T2 = *(const float4*)(tbl + pq2_ * HID);  \
    T3 = *(const float4*)(tbl + pq3_ * HID);  \
  }

// One step. P_ = prefolded scaled input (r*wb' + T').
// c_j = 1/(exp2(x'_j)+1); q = sum w2n_j*c_j ; after quad-reduce:
// upd+b2 = q + W2pb. z = state + AF_*(q+W2pb); sigmoid.
#define STEP(P_, AF_, STO_)                                             \
  {                                                                     \
    float x0_k = fmaf(state, wav.x, P_.x);                              \
    float x1_k = fmaf(state, wav.y, P_.y);                              \
    float x2_k = fmaf(state, wav.z, P_.z);                              \
    float x3_k = fmaf(state, wav.w, P_.w);                              \
    x0_k = fmaxf(x0_k, 0.f);                                            \
    x1_k = fmaxf(x1_k, 0.f);                                            \
    x2_k = fmaxf(x2_k, 0.f);                                            \
    x3_k = fmaxf(x3_k, 0.f);                                            \
    float c0_k = __builtin_amdgcn_rcpf(__builtin_amdgcn_exp2f(x0_k) + 1.f); \
    float c1_k = __builtin_amdgcn_rcpf(__builtin_amdgcn_exp2f(x1_k) + 1.f); \
    float c2_k = __builtin_amdgcn_rcpf(__builtin_amdgcn_exp2f(x2_k) + 1.f); \
    float c3_k = __builtin_amdgcn_rcpf(__builtin_amdgcn_exp2f(x3_k) + 1.f); \
    float q_k = c0_k * w2n.x;                                           \
    q_k = fmaf(c1_k, w2n.y, q_k);                                       \
    q_k = fmaf(c2_k, w2n.z, q_k);                                       \
    q_k = fmaf(c3_k, w2n.w, q_k);                                       \
    q_k += dppf<0xB1>(q_k); /* xor1 */                                  \
    q_k += dppf<0x4E>(q_k); /* xor2 */                                  \
    float z_k = fmaf(AF_, q_k + W2pb, state); /* AF_ in {0.,1.} */      \
    state = __builtin_amdgcn_rcpf(                                      \
        1.f + __builtin_amdgcn_exp2f(z_k * -1.4426950408889634f));      \
    STO_ = state;                                                       \
  }

#define PROLOGUE(G0_)                 \
  LOAD_RAW(G0_, rA, aA, pA);          \
  LOAD_RAW((G0_) + 1, rB, aB, pB);    \
  GATHER(pA, t0, t1, t2, t3);

// One group-of-4 loop with LITERAL bounds. DOST_ is a literal 0/1.
#define SCAN_LOOP(G0_, G1_, DOST_)                                     \
  _Pragma("unroll 2")                                                  \
  for (int g = G0_; g < G1_; ++g) {                                    \
    LOAD_RAW(g + 2, rC, aC, pC);       /* raw: 2-group lead */         \
    float4 u0, u1, u2, u3;                                             \
    GATHER(pB, u0, u1, u2, u3);        /* table: 1-group lead */       \
    float r0 = dppf<BC(0)>(rA), r1 = dppf<BC(1)>(rA);                  \
    float r2 = dppf<BC(2)>(rA), r3 = dppf<BC(3)>(rA);                  \
    float afq = (float)aA;                                             \
    float af0 = dppf<BC(0)>(afq), af1 = dppf<BC(1)>(afq);              \
    float af2 = dppf<BC(2)>(afq), af3 = dppf<BC(3)>(afq);              \
    float4 p0, p1, p2, p3;                                             \
    p0.x = fmaf(r0, wbv.x, t0.x); p0.y = fmaf(r0, wbv.y, t0.y);        \
    p0.z = fmaf(r0, wbv.z, t0.z); p0.w = fmaf(r0, wbv.w, t0.w);        \
    p1.x = fmaf(r1, wbv.x, t1.x); p1.y = fmaf(r1, wbv.y, t1.y);        \
    p1.z = fmaf(r1, wbv.z, t1.z); p1.w = fmaf(r1, wbv.w, t1.w);        \
    p2.x = fmaf(r2, wbv.x, t2.x); p2.y = fmaf(r2, wbv.y, t2.y);        \
    p2.z = fmaf(r2, wbv.z, t2.z); p2.w = fmaf(r2, wbv.w, t2.w);        \
    p3.x = fmaf(r3, wbv.x, t3.x); p3.y = fmaf(r3, wbv.y, t3.y);        \
    p3.z = fmaf(r3, wbv.z, t3.z); p3.w = fmaf(r3, wbv.w, t3.w);        \
    float s0, s1, s2, s3;                                              \
    STEP(p0, af0, s0);                                                 \
    STEP(p1, af1, s1);                                                 \
    STEP(p2, af2, s2);                                                 \
    STEP(p3, af3, s3);                                                 \
    if (DOST_) {                                                       \
      float sv = (sub & 1) ? s1 : s0;                                  \
      float sw = (sub & 1) ? s3 : s2;                                  \
      sv = (sub & 2) ? sw : sv;                                        \
      op[(size_t)(g * 4 + sub) * BA] = sv;                             \
    }                                                                  \
    rA = rB; aA = aB;                                                  \
    rB = rC; aB = aC; pB = pC;                                         \
    t0 = u0; t1 = u1; t2 = u2; t3 = u3;                                \
  }

  float rA, rB, rC;
  int aA, aB, aC, pA, pB, pC;
  float4 t0, t1, t2, t3;
  float state;

  if (seg == 0) {
    state = 0.f;
    PROLOGUE(0);
    SCAN_LOOP(0, 67, 1);    // 67 groups of work
  } else {
    state = 0.5f;  // contraction warm-up init
    PROLOGUE(61);
    SCAN_LOOP(61, 67, 0);   // 24 warm-up steps, no stores
    SCAN_LOOP(67, 128, 1);  // output steps 268..511 -> 67 groups total
  }
}

extern "C" void kernel_launch(void* const* d_in, const int* in_sizes, int n_in,
                              void* d_out, int out_size, void* d_ws, size_t ws_size,
                              hipStream_t stream) {
  const int* c_Action = (const int*)d_in[0];
  const float* c_Reward = (const float*)d_in[1];
  const int* c_ParticipantID = (const int*)d_in[2];
  const float* emb_table = (const float*)d_in[3];
  const float* W1 = (const float*)d_in[4];
  const float* b1 = (const float*)d_in[5];
  const float* W2 = (const float*)d_in[6];
  const float* b2 = (const float*)d_in[7];
  float* out = (float*)d_out;
  float* proj = (float*)d_ws;  // 16000 floats = 64 KB scratch

  emb_proj_kernel<<<(TABN + 255) / 256, 256, 0, stream>>>(emb_table, W1, b1, proj);

  // 32768 chains * 4 lanes * 2 balanced time-segments = 262144 threads;
  // 1024 blocks -> 4 waves/SIMD
  scan_kernel<<<1024, 256, 0, stream>>>(
      c_Action, c_Reward, c_ParticipantID, W1, W2, b2, proj, out);
}